// Round 9
// baseline (171.018 us; speedup 1.0000x reference)
//
#include <hip/hip_runtime.h>
#include <stdint.h>

typedef unsigned short u16;
typedef __attribute__((ext_vector_type(8))) short bf16x8;   // 8 bf16 in 4 VGPRs
typedef __attribute__((ext_vector_type(4))) float floatx4;

#define MFMA16(a, b, c) __builtin_amdgcn_mfma_f32_16x16x32_bf16(a, b, c, 0, 0, 0)
#define MEMFENCE asm volatile("" ::: "memory")
// wave-local waits: compiler does NOT track glds->ds_read dependencies
#define WAIT_VM0 asm volatile("s_waitcnt vmcnt(0)" ::: "memory")
#define WAIT_LGKM0 asm volatile("s_waitcnt lgkmcnt(0)" ::: "memory")

#if __has_builtin(__builtin_amdgcn_exp2f)
#define EXP2(x) __builtin_amdgcn_exp2f(x)
#else
#define EXP2(x) __expf(0.6931471805599453f * (x))
#endif

__device__ __forceinline__ u16 f2bf(float f) {   // round-to-nearest-even
  unsigned u = __builtin_bit_cast(unsigned, f);
  return (u16)((u + 0x7FFFu + ((u >> 16) & 1u)) >> 16);
}
__device__ __forceinline__ u16 f2bf_hu(float f) {  // round-half-up (cheaper)
  return (u16)((__builtin_bit_cast(unsigned, f) + 0x8000u) >> 16);
}
__device__ __forceinline__ float bf2f(u16 v) {
  return __builtin_bit_cast(float, (unsigned)v << 16);
}

// async global->LDS, 16B/lane. LDS dest = wave-uniform base + lane*16 (HW).
__device__ __forceinline__ void glds16(void* lds, const void* g) {
  __builtin_amdgcn_global_load_lds((const __attribute__((address_space(1))) void*)g,
                                   (__attribute__((address_space(3))) void*)lds,
                                   16, 0, 0);
}

// ---------------------------------------------------------------- convert
__global__ __launch_bounds__(256) void cvt_all(
    const float* __restrict__ x, const float* __restrict__ w0,
    const float* __restrict__ w1, const float* __restrict__ w2,
    u16* __restrict__ xb, u16* __restrict__ Wb) {
  const int bid = blockIdx.x;
  const float* src;
  u16* dst;
  int i;
  if (bid < 4096) {
    src = x; dst = xb; i = bid * 256 + threadIdx.x;
  } else {
    const int z = (bid - 4096) >> 10;
    src = (z == 0) ? w0 : (z == 1) ? w1 : w2;
    dst = Wb + (size_t)z * (1024 * 1024);
    i = ((bid - 4096) & 1023) * 256 + threadIdx.x;
  }
  float4 f = reinterpret_cast<const float4*>(src)[i];
  ushort4 o;
  o.x = f2bf(f.x); o.y = f2bf(f.y); o.z = f2bf(f.z); o.w = f2bf(f.w);
  reinterpret_cast<ushort4*>(dst)[i] = o;
}

// ---------------------------------------------------------------- QKV GEMM
// (unchanged from R8 — proven). 128x128 tile, BK=64, 768 blocks = 3/CU,
// XOR-swizzled LDS. which=0 -> Q (pre-scaled 0.25*log2e), 1 -> K, 2 -> V^T.
__global__ __launch_bounds__(256, 3) void qkv_gemm(
    const u16* __restrict__ xb, const u16* __restrict__ Wb,
    const float* __restrict__ bq, const float* __restrict__ bk,
    const float* __restrict__ bv,
    u16* __restrict__ Qb, u16* __restrict__ Kb, u16* __restrict__ VTb) {
  __shared__ __attribute__((aligned(16))) u16 smem[2 * 128 * 64];   // 32KB
  u16* As = smem;
  u16* Bs = smem + 128 * 64;

  const int tid = threadIdx.x;
  const int w = tid >> 6, lane = tid & 63;
  const int lo = lane & 15, quad = lane >> 4;
  const int which = blockIdx.z;
  const int m0 = blockIdx.x * 128, n0 = blockIdx.y * 128;

  const u16* W = Wb + (size_t)which * (1024 * 1024);
  const int wm = (w >> 1) * 64, wn = (w & 1) * 64;

  floatx4 acc[4][4];
  for (int i = 0; i < 4; ++i)
    for (int j = 0; j < 4; ++j) acc[i][j] = (floatx4)0.f;

  const int arow = lane >> 3;
  const int aswz = ((lane & 7) ^ arow) * 8;

  for (int kt = 0; kt < 16; ++kt) {
    const int k0 = kt * 64;
    for (int j = 0; j < 4; ++j) {
      const int seg = w * 4 + j;
      glds16(As + seg * 512, xb + (size_t)(m0 + seg * 8 + arow) * 1024 + k0 + aswz);
      glds16(Bs + seg * 512, W + (size_t)(n0 + seg * 8 + arow) * 1024 + k0 + aswz);
    }
    __syncthreads();
    for (int kk = 0; kk < 2; ++kk) {
      const int swz = ((kk * 4 + quad) ^ (lo & 7)) * 8;
      bf16x8 af[4], bfr[4];
      for (int it = 0; it < 4; ++it)
        af[it] = *reinterpret_cast<const bf16x8*>(As + (wm + it * 16 + lo) * 64 + swz);
      for (int jt = 0; jt < 4; ++jt)
        bfr[jt] = *reinterpret_cast<const bf16x8*>(Bs + (wn + jt * 16 + lo) * 64 + swz);
      for (int it = 0; it < 4; ++it)
        for (int jt = 0; jt < 4; ++jt)
          acc[it][jt] = MFMA16(af[it], bfr[jt], acc[it][jt]);
    }
    __syncthreads();
  }

  const float* bias = (which == 0) ? bq : (which == 1) ? bk : bv;
  float bb[4];
  for (int jt = 0; jt < 4; ++jt) bb[jt] = bias[n0 + wn + jt * 16 + lo];
  const int b = m0 >> 11;

  if (which < 2) {
    const float scl = (which == 0) ? 0.36067376022224085f : 1.0f;  // 0.25*log2e
    u16* Tw = smem + w * (16 * 72);
    const int hblk = (n0 + wn) >> 6;
    u16* dst = ((which == 0) ? Qb : Kb) +
               ((size_t)(b * 16 + hblk) * 2048 + ((m0 & 2047) + wm)) * 64;
    for (int it = 0; it < 4; ++it) {
      for (int jt = 0; jt < 4; ++jt)
        for (int r = 0; r < 4; ++r) {
          const int m = quad * 4 + r, col = jt * 16 + lo;
          Tw[m * 72 + (((col >> 3) ^ (m & 7)) * 8) + (col & 7)] =
              f2bf((acc[it][jt][r] + bb[jt]) * scl);
        }
      MEMFENCE;
      for (int rd = 0; rd < 2; ++rd) {
        const int sr = rd * 8 + (lane >> 3), d8 = lane & 7;
        bf16x8 v = *reinterpret_cast<const bf16x8*>(Tw + sr * 72 + ((d8 ^ (sr & 7)) * 8));
        *reinterpret_cast<bf16x8*>(dst + (size_t)(it * 16 + sr) * 64 + d8 * 8) = v;
      }
      MEMFENCE;
    }
  } else {
    for (int pass = 0; pass < 2; ++pass) {
      if ((wm >> 6) == pass) {
        for (int it = 0; it < 4; ++it)
          for (int jt = 0; jt < 4; ++jt)
            for (int r = 0; r < 4; ++r) {
              const int n = wn + jt * 16 + lo;
              const int m = it * 16 + quad * 4 + r;
              smem[n * 72 + (((m >> 3) ^ (n & 7)) * 8) + (m & 7)] =
                  f2bf(acc[it][jt][r] + bb[jt]);
            }
      }
      __syncthreads();
      for (int rd = 0; rd < 4; ++rd) {
        const int n = (tid >> 3) + rd * 32, m8 = tid & 7;
        bf16x8 v = *reinterpret_cast<const bf16x8*>(smem + n * 72 + ((m8 ^ (n & 7)) * 8));
        const int ng = n0 + n, h = ng >> 6, d = ng & 63;
        const int s = (m0 & 2047) + pass * 64 + m8 * 8;
        *reinterpret_cast<bf16x8*>(VTb + ((size_t)(b * 16 + h) * 64 + d) * 2048 + s) = v;
      }
      __syncthreads();
    }
  }
}

// ---------------------------------------------------------------- attention
// 1-wave blocks, ZERO barriers. Each wave independently processes the q-tile
// pair {qt, 63-qt} (32 q each, sequential phases) => EVERY block = exactly 33
// k-iterations (fixes R8's 12%-occupancy concurrency hole: co-resident blocks
// all equal length). Private K/V staging per wave (single buffer, 16 glds),
// synced by wave-local s_waitcnt vmcnt/lgkm (no __syncthreads => no vmcnt(0)
// lockstep drain). Fixed-max softmax p=exp2(s') (shift-invariant, bounded);
// per-key mask only on each phase's first k-tile. Per-wave math identical to
// R8's proven wave code. LDS 20KB/block -> 8 blocks/CU. Row 2047 -> fix2047.
__global__ __launch_bounds__(64, 2) void attn(
    const u16* __restrict__ Qb, const u16* __restrict__ Kb,
    const u16* __restrict__ VTb, float* __restrict__ out) {
  __shared__ __attribute__((aligned(16))) u16 Ks[64 * 64];   // 8KB [key][d] swz
  __shared__ __attribute__((aligned(16))) u16 Vs[64 * 64];   // 8KB [d][key] swz
  __shared__ __attribute__((aligned(16))) u16 Pt[2][16 * 64];// 4KB per-qset

  const int L = blockIdx.x;        // 1024 blocks
  const int bh = L & 31;           // bh%8 = L%8 -> 4 bh per XCD (L2 locality)
  const int qtA = L >> 5;          // 0..31; pair = {qtA, 63-qtA} -> 33 iters

  const int lane = threadIdx.x & 63;
  const int lo = lane & 15, quad = lane >> 4;

  const u16* Qh = Qb + (size_t)bh * (2048 * 64);
  const u16* Kh = Kb + (size_t)bh * (2048 * 64);
  const u16* Vh = VTb + (size_t)bh * (64 * 2048);

  const int srow8 = lane >> 3, sblk = lane & 7;
  const int sswz = (sblk ^ srow8) * 8;          // staging XOR swizzle
  const int b = bh >> 4, hh = bh & 15;

  // stage 64-key tile kt into the single K/V buffer (16 glds, wave-local)
#define STAGE(kt)                                                             \
  for (int j = 0; j < 8; ++j) {                                               \
    glds16(&Ks[j * 512], Kh + (size_t)((kt) * 64 + j * 8 + srow8) * 64 + sswz); \
    glds16(&Vs[j * 512], Vh + (size_t)(j * 8 + srow8) * 2048 + (kt) * 64 + sswz); \
  }

  { STAGE(qtA >> 1); }   // prologue: phase A's first tile

  for (int p = 0; p < 2; ++p) {
    const int qtp = (p == 0) ? qtA : 63 - qtA;
    const int kstart = qtp >> 1;
    const int n = 32 - kstart;

    int qrow[2];
    bf16x8 qf[2][2];
    for (int s = 0; s < 2; ++s) {
      qrow[s] = qtp * 32 + s * 16 + lo;
      qf[s][0] = *reinterpret_cast<const bf16x8*>(Qh + (size_t)qrow[s] * 64 + quad * 8);
      qf[s][1] = *reinterpret_cast<const bf16x8*>(Qh + (size_t)qrow[s] * 64 + 32 + quad * 8);
    }

    float lrun[2] = {0.f, 0.f};
    floatx4 acc[2][4];
    for (int s = 0; s < 2; ++s)
      for (int dt = 0; dt < 4; ++dt) acc[s][dt] = (floatx4)0.f;

    for (int i = 0; i < n; ++i) {
      const int kt = kstart + i;
      WAIT_VM0;      // staged tile (and qf loads) landed
      MEMFENCE;

      // QK (A=K frags) + V frags into registers (shared across both qsets)
      floatx4 sc[2][4];
      for (int s = 0; s < 2; ++s)
        for (int t = 0; t < 4; ++t) sc[s][t] = (floatx4)0.f;
      bf16x8 va[2][4];
      for (int kk = 0; kk < 2; ++kk) {
        const int swz = ((kk * 4 + quad) ^ (lo & 7)) * 8;
        for (int t = 0; t < 4; ++t) {
          bf16x8 ka = *reinterpret_cast<const bf16x8*>(Ks + (t * 16 + lo) * 64 + swz);
          sc[0][t] = MFMA16(ka, qf[0][kk], sc[0][t]);
          sc[1][t] = MFMA16(ka, qf[1][kk], sc[1][t]);
        }
        for (int dt = 0; dt < 4; ++dt)
          va[kk][dt] = *reinterpret_cast<const bf16x8*>(Vs + (dt * 16 + lo) * 64 + swz);
      }

      const bool maskp = (i == 0);   // only the phase's first tile is partial
      for (int s = 0; s < 2; ++s) {
        u16* ptw = &Pt[s][0];
        for (int t = 0; t < 4; ++t) {
          float p0 = EXP2(sc[s][t][0]), p1 = EXP2(sc[s][t][1]);
          float p2 = EXP2(sc[s][t][2]), p3 = EXP2(sc[s][t][3]);
          if (maskp) {   // faithful buggy mask: keep key > q
            const int key = kt * 64 + t * 16 + quad * 4;
            p0 = (key + 0 > qrow[s]) ? p0 : 0.f;
            p1 = (key + 1 > qrow[s]) ? p1 : 0.f;
            p2 = (key + 2 > qrow[s]) ? p2 : 0.f;
            p3 = (key + 3 > qrow[s]) ? p3 : 0.f;
          }
          lrun[s] += (p0 + p1) + (p2 + p3);
          ushort4 pk;
          pk.x = f2bf_hu(p0); pk.y = f2bf_hu(p1);
          pk.z = f2bf_hu(p2); pk.w = f2bf_hu(p3);
          u16* pdst = ptw + lo * 64 +
                      (((2 * t + (quad >> 1)) ^ (lo & 7)) * 8) + (quad & 1) * 4;
          *reinterpret_cast<ushort4*>(pdst) = pk;
        }
      }
      MEMFENCE;   // Pt writes ordered before Pt reads (same wave)

      bf16x8 pb[2][2];
      for (int kk = 0; kk < 2; ++kk) {
        const int pswz = ((kk * 4 + quad) ^ (lo & 7)) * 8;
        pb[0][kk] = *reinterpret_cast<const bf16x8*>(&Pt[0][lo * 64] + pswz);
        pb[1][kk] = *reinterpret_cast<const bf16x8*>(&Pt[1][lo * 64] + pswz);
      }
      WAIT_LGKM0;   // ALL LDS reads of this tile complete -> buffer reusable
      MEMFENCE;

      // stage next tile (same phase, or phase B's first) under the PV MFMAs
      if (i + 1 < n) { STAGE(kt + 1); }
      else if (p == 0) { STAGE((63 - qtA) >> 1); }

      for (int kk = 0; kk < 2; ++kk)
        for (int dt = 0; dt < 4; ++dt) {
          acc[0][dt] = MFMA16(va[kk][dt], pb[0][kk], acc[0][dt]);
          acc[1][dt] = MFMA16(va[kk][dt], pb[1][kk], acc[1][dt]);
        }
    }

    // phase epilogue (no LDS; phase-B staging may still be in flight)
    for (int s = 0; s < 2; ++s) {
      float l = lrun[s];
      l += __shfl_xor(l, 16);
      l += __shfl_xor(l, 32);
      if (l != 0.f) {   // l==0 only for fully-masked row 2047 (fix2047)
        const float rl = 1.f / l;
        float* op = out + ((size_t)(b * 2048 + qrow[s])) * 1024 + hh * 64 + quad * 4;
        for (int dt = 0; dt < 4; ++dt) {
          float4 o4;
          o4.x = acc[s][dt][0] * rl; o4.y = acc[s][dt][1] * rl;
          o4.z = acc[s][dt][2] * rl; o4.w = acc[s][dt][3] * rl;
          *reinterpret_cast<float4*>(op + dt * 16) = o4;
        }
      }
    }
  }
#undef STAGE
}

// ---------------------------------------------------------------- fix2047
// Row 2047 fully masked -> uniform softmax: out = mean_s V[b,s,:].
__global__ __launch_bounds__(256) void fix2047(const u16* __restrict__ VTb,
                                               float* __restrict__ out) {
  const int bh = blockIdx.x;
  const u16* Vh = VTb + (size_t)bh * (64 * 2048);
  const int t = threadIdx.x;
  const int d = t >> 2, j = t & 3;
  float s = 0.f;
  const u16* row = Vh + (size_t)d * 2048 + j * 512;
  for (int i = 0; i < 64; ++i) {
    bf16x8 v = *reinterpret_cast<const bf16x8*>(row + i * 8);
    for (int e = 0; e < 8; ++e) s += bf2f((u16)v[e]);
  }
  s += __shfl_xor(s, 1);
  s += __shfl_xor(s, 2);
  if (j == 0) {
    const int b = bh >> 4, h = bh & 15;
    out[((size_t)(b * 2048 + 2047)) * 1024 + h * 64 + d] = s * (1.f / 2048.f);
  }
}

// ---------------------------------------------------------------- launch
extern "C" void kernel_launch(void* const* d_in, const int* in_sizes, int n_in,
                              void* d_out, int out_size, void* d_ws, size_t ws_size,
                              hipStream_t stream) {
  const float* x  = (const float*)d_in[0];
  const float* Wq = (const float*)d_in[1];
  const float* bq = (const float*)d_in[2];
  const float* Wk = (const float*)d_in[3];
  const float* bk = (const float*)d_in[4];
  const float* Wv = (const float*)d_in[5];
  const float* bv = (const float*)d_in[6];
  float* out = (float*)d_out;

  char* ws = (char*)d_ws;
  u16* xb  = (u16*)(ws);                  // 8 MB: x as bf16 [4096][1024]
  u16* Wb  = (u16*)(ws + (8u << 20));     // 6 MB: Wq,Wk,Wv bf16
  u16* Qb  = (u16*)(ws + (14u << 20));    // 8 MB: Q  [B,H,S,dh] (pre-scaled)
  u16* Kb  = (u16*)(ws + (22u << 20));    // 8 MB: K  [B,H,S,dh]
  u16* VTb = (u16*)(ws + (30u << 20));    // 8 MB: V^T [B,H,dh,S]

  cvt_all<<<7168, 256, 0, stream>>>(x, Wq, Wk, Wv, xb, Wb);
  qkv_gemm<<<dim3(32, 8, 3), 256, 0, stream>>>(xb, Wb, bq, bk, bv, Qb, Kb, VTb);
  attn<<<dim3(1024), 64, 0, stream>>>(Qb, Kb, VTb, out);
  fix2047<<<dim3(32), 256, 0, stream>>>(VTb, out);
}